// Round 6
// baseline (587.619 us; speedup 1.0000x reference)
//
#include <hip/hip_runtime.h>

#define NFOLDS 12
#define EPS 1e-8f
#define BATCH 2048
#define IN_DIM 128
#define UNITS 256
#define RB 4
#define LOG2E 1.44269504088896340736f
#define VCLAMP 4.5f

#if __has_builtin(__builtin_amdgcn_rcpf)
#define RCPF(x) __builtin_amdgcn_rcpf(x)
#else
#define RCPF(x) (1.0f / (x))
#endif

typedef float f2 __attribute__((ext_vector_type(2)));
typedef float f4 __attribute__((ext_vector_type(4)));
typedef unsigned int u2 __attribute__((ext_vector_type(2)));

// Schraudolph magic: z = t + C rounds t to nearest int n (RTNE); low bits of
// z's int repr hold n+127, so bitcast(z_bits << 23) == 2^n. Valid |t| <= 126;
// here |t| <= 62 via the +-4.5 input clamp.
#define MAGIC_C 12583039.0f   // 1.5*2^23 + 127
#define RCP_MAGIC 0x7EF311C7u

// Taylor deg-4 for 2^f on [-0.5, 0.5], rel err ~4.2e-5
#define EC1 0.6931471805599453f
#define EC2 0.2402265069591007f
#define EC3 0.0555041086648216f
#define EC4 0.0096181291076285f

// ---- guaranteed-packed fp32 ops (VOP3P) ----
__device__ __forceinline__ f2 pk_fma(f2 a, f2 b, f2 c) {
    f2 d;
    asm("v_pk_fma_f32 %0, %1, %2, %3" : "=v"(d) : "v"(a), "v"(b), "v"(c));
    return d;
}
__device__ __forceinline__ f2 pk_add(f2 a, f2 b) {
    f2 d;
    asm("v_pk_add_f32 %0, %1, %2" : "=v"(d) : "v"(a), "v"(b));
    return d;
}
__device__ __forceinline__ f2 pk_mul(f2 a, f2 b) {
    f2 d;
    asm("v_pk_mul_f32 %0, %1, %2" : "=v"(d) : "v"(a), "v"(b));
    return d;
}

struct SigK {
    f2 C2, negC2, one2, negone2, c1, c2, c3, c4;
};

// One synapse pair, all float math in packed asm; only int ops (2 shl, 2 sub)
// in HIP code (scalarized but regalloc-coalescable into the consuming pair).
//   t = a*v + b ; 2^t = poly(f) * 2^n via magic round ; A = 1 + 2^t
//   r = 1/A via bit-trick init + 2 packed Newton ; red += w*r ; num += we*r
__device__ __forceinline__ void syn2(const f2 a, const f2 b, const f2 w,
                                     const f2 we, const f2 v2, const SigK& K,
                                     f2& red, f2& num) {
    f2 t = pk_fma(a, v2, b);
    f2 z = pk_add(t, K.C2);            // n = round(t) encoded in mantissa
    f2 n = pk_add(z, K.negC2);         // n as float (exact)
    f2 f = pk_fma(n, K.negone2, t);    // f = t - n in [-0.5, 0.5] (exact)
    f2 p = pk_fma(K.c4, f, K.c3);
    p = pk_fma(p, f, K.c2);
    p = pk_fma(p, f, K.c1);
    p = pk_fma(p, f, K.one2);          // p = 2^f
    u2 s = __builtin_bit_cast(u2, z) << 23;              // 2^n bits
    f2 A = pk_fma(p, __builtin_bit_cast(f2, s), K.one2); // A = 1 + 2^t
    u2 ri = (u2){RCP_MAGIC, RCP_MAGIC} - __builtin_bit_cast(u2, A);
    f2 r = __builtin_bit_cast(f2, ri); // ~5% reciprocal seed
    f2 nA = pk_mul(A, K.negone2);
    f2 e = pk_fma(nA, r, K.one2);
    r = pk_fma(r, e, r);
    e = pk_fma(nA, r, K.one2);
    r = pk_fma(r, e, r);               // r = 1/A = sigmoid, rel err ~4e-5
    red = pk_fma(w, r, red);
    num = pk_fma(we, r, num);
}

// Quad-packed params: for row-quad q (rows 4q..4q+3), col u:
//   outA = {-A0..-A3}, outB = {A*mu}, outW = {W}, outE = {W*erev}
__global__ void prep_quad_kernel(const float* __restrict__ mu,
                                 const float* __restrict__ sigma,
                                 const float* __restrict__ W,
                                 const float* __restrict__ erev,
                                 f4* __restrict__ outA, f4* __restrict__ outB,
                                 f4* __restrict__ outW, f4* __restrict__ outE,
                                 int n) {
    int i = blockIdx.x * blockDim.x + threadIdx.x;  // i = q*UNITS + u
    if (i < n) {
        int q = i >> 8;
        int u = i & (UNITS - 1);
        f4 A, B, Wv, E;
        #pragma unroll
        for (int k = 0; k < 4; ++k) {
            int idx = (4 * q + k) * UNITS + u;
            float Ak = sigma[idx] * LOG2E;
            A[k] = -Ak;
            B[k] = Ak * mu[idx];
            Wv[k] = W[idx];
            E[k] = W[idx] * erev[idx];
        }
        outA[i] = A; outB[i] = B; outW[i] = Wv; outE[i] = E;
    }
}

#define LO(q) __builtin_shufflevector(q, q, 0, 1)
#define HI(q) __builtin_shufflevector(q, q, 2, 3)

// Block: 512 threads = (u: 0..255) x (h: reduction half 0..1). RB=4 rows.
__global__ __launch_bounds__(512, 4) void ltc_kernel(
    const f4* __restrict__ rA, const f4* __restrict__ rB,   // [UNITS/4][UNITS]
    const f4* __restrict__ rW, const f4* __restrict__ rE,
    const f4* __restrict__ sA, const f4* __restrict__ sB,   // [IN_DIM/4][UNITS]
    const f4* __restrict__ sW, const f4* __restrict__ sE,
    const float* __restrict__ inputs, // [BATCH][IN_DIM]
    const float* __restrict__ state,  // [BATCH][UNITS]
    const float* __restrict__ vleak,
    const float* __restrict__ gleak,
    const float* __restrict__ cm_t,
    float* __restrict__ out)          // [BATCH][UNITS]
{
    const int tid = threadIdx.x;
    const int u = tid & (UNITS - 1);
    const int h = tid >> 8;
    const int b0 = blockIdx.x * RB;

    SigK K;
    K.C2 = f2{MAGIC_C, MAGIC_C};
    K.negC2 = f2{-MAGIC_C, -MAGIC_C};
    K.one2 = f2{1.0f, 1.0f};
    K.negone2 = f2{-1.0f, -1.0f};
    K.c1 = f2{EC1, EC1};
    K.c2 = f2{EC2, EC2};
    K.c3 = f2{EC3, EC3};
    K.c4 = f2{EC4, EC4};

    __shared__ __align__(16) float v_sh[RB][UNITS];
    __shared__ __align__(16) float in_sh[RB][IN_DIM];
    __shared__ float nb_sh[RB][UNITS];   // glvl + snum
    __shared__ float db_sh[RB][UNITS];   // cm + gl + sden + EPS
    __shared__ float cm_sh[UNITS];
    __shared__ float pred[2][RB][UNITS];
    __shared__ float pnum[2][RB][UNITS];

    // ---- stage rows. v_sh holds CLAMPED v (synapse input only; |t|<=62).
    //      Unclamped v kept in registers for the cm*v term. ----
    if (h == 0) {
        #pragma unroll
        for (int rb = 0; rb < RB; ++rb) {
            float s = state[(b0 + rb) * UNITS + u];
            v_sh[rb][u] = fminf(fmaxf(s, -VCLAMP), VCLAMP);
        }
        cm_sh[u] = cm_t[u];
    } else {
        #pragma unroll
        for (int k = u; k < RB * IN_DIM; k += UNITS) {
            int rb = k >> 7;
            int i  = k & (IN_DIM - 1);
            float x = inputs[(b0 + rb) * IN_DIM + i];
            in_sh[rb][i] = fminf(fmaxf(x, -VCLAMP), VCLAMP);
        }
    }
    float vfull[2];
    #pragma unroll
    for (int k = 0; k < 2; ++k)
        vfull[k] = state[(b0 + h + 2 * k) * UNITS + u];
    __syncthreads();

    // ---- sensory path: half h sums i in [h*64, h*64+64) = 16 quads ----
    {
        f2 sden[RB] = {{0.f,0.f},{0.f,0.f},{0.f,0.f},{0.f,0.f}};
        f2 snum[RB] = {{0.f,0.f},{0.f,0.f},{0.f,0.f},{0.f,0.f}};
        const int ibase = h * (IN_DIM / 2);
        for (int ic = 0; ic < IN_DIM / 2; ic += 4) {
            const int i = ibase + ic;
            const int qd = i >> 2;
            f4 qa = sA[qd * UNITS + u];
            f4 qb = sB[qd * UNITS + u];
            f4 qw = sW[qd * UNITS + u];
            f4 qe = sE[qd * UNITS + u];
            #pragma unroll
            for (int rb = 0; rb < RB; ++rb) {
                f4 x4 = *reinterpret_cast<const f4*>(&in_sh[rb][i]);
                syn2(LO(qa), LO(qb), LO(qw), LO(qe), LO(x4), K, sden[rb], snum[rb]);
                syn2(HI(qa), HI(qb), HI(qw), HI(qe), HI(x4), K, sden[rb], snum[rb]);
            }
        }
        #pragma unroll
        for (int rb = 0; rb < RB; ++rb) {
            pred[h][rb][u] = sden[rb].x + sden[rb].y;
            pnum[h][rb][u] = snum[rb].x + snum[rb].y;
        }
    }
    __syncthreads();

    // combine sensory partials into per-(rb,u) bases
    #pragma unroll
    for (int k = 0; k < 2; ++k) {
        const int rb = h + 2 * k;
        float gl = gleak[u];
        float sd = pred[0][rb][u] + pred[1][rb][u];
        float sn = pnum[0][rb][u] + pnum[1][rb][u];
        db_sh[rb][u] = cm_sh[u] + gl + sd + EPS;
        nb_sh[rb][u] = fmaf(gl, vleak[u], sn);
    }
    __syncthreads();

    // ---- 12 folds: half h reduces j in [h*128, h*128+128) = 32 quads ----
    for (int f = 0; f < NFOLDS; ++f) {
        f2 wred[RB] = {{0.f,0.f},{0.f,0.f},{0.f,0.f},{0.f,0.f}};
        f2 wnum[RB] = {{0.f,0.f},{0.f,0.f},{0.f,0.f},{0.f,0.f}};
        const int jbase = h * (UNITS / 2);
        for (int jc = 0; jc < UNITS / 2; jc += 4) {
            const int j = jbase + jc;
            const int qd = j >> 2;
            f4 qa = rA[qd * UNITS + u];
            f4 qb = rB[qd * UNITS + u];
            f4 qw = rW[qd * UNITS + u];
            f4 qe = rE[qd * UNITS + u];
            #pragma unroll
            for (int rb = 0; rb < RB; ++rb) {
                f4 v4 = *reinterpret_cast<const f4*>(&v_sh[rb][j]);
                syn2(LO(qa), LO(qb), LO(qw), LO(qe), LO(v4), K, wred[rb], wnum[rb]);
                syn2(HI(qa), HI(qb), HI(qw), HI(qe), HI(v4), K, wred[rb], wnum[rb]);
            }
        }
        #pragma unroll
        for (int rb = 0; rb < RB; ++rb) {
            pred[h][rb][u] = wred[rb].x + wred[rb].y;
            pnum[h][rb][u] = wnum[rb].x + wnum[rb].y;
        }
        __syncthreads();

        #pragma unroll
        for (int k = 0; k < 2; ++k) {
            const int rb = h + 2 * k;
            float wr = pred[0][rb][u] + pred[1][rb][u];
            float wn = pnum[0][rb][u] + pnum[1][rb][u];
            float num = fmaf(cm_sh[u], vfull[k], nb_sh[rb][u]) + wn;
            float den = db_sh[rb][u] + wr;
            float vn = num * RCPF(den);
            vfull[k] = vn;                                   // exact v for cm*v
            v_sh[rb][u] = fminf(fmaxf(vn, -VCLAMP), VCLAMP); // synapse input
            if (f == NFOLDS - 1)
                out[(b0 + rb) * UNITS + u] = vn;
        }
        __syncthreads();
    }
}

extern "C" void kernel_launch(void* const* d_in, const int* in_sizes, int n_in,
                              void* d_out, int out_size, void* d_ws, size_t ws_size,
                              hipStream_t stream) {
    const float* inputs       = (const float*)d_in[0];
    const float* state        = (const float*)d_in[1];
    const float* sensory_mu   = (const float*)d_in[2];
    const float* sensory_sig  = (const float*)d_in[3];
    const float* sensory_W    = (const float*)d_in[4];
    const float* sensory_erev = (const float*)d_in[5];
    const float* mu           = (const float*)d_in[6];
    const float* sigma        = (const float*)d_in[7];
    const float* W            = (const float*)d_in[8];
    const float* erev         = (const float*)d_in[9];
    const float* vleak        = (const float*)d_in[10];
    const float* gleak        = (const float*)d_in[11];
    const float* cm_t         = (const float*)d_in[12];
    float* out = (float*)d_out;

    // workspace: 4 recurrent quad arrays (64x256 f4) + 4 sensory (32x256 f4)
    f4* rA = (f4*)d_ws;
    f4* rB = rA + (UNITS / 4) * UNITS;
    f4* rW = rB + (UNITS / 4) * UNITS;
    f4* rE = rW + (UNITS / 4) * UNITS;
    f4* sA = rE + (UNITS / 4) * UNITS;
    f4* sB = sA + (IN_DIM / 4) * UNITS;
    f4* sW = sB + (IN_DIM / 4) * UNITS;
    f4* sE = sW + (IN_DIM / 4) * UNITS;

    int n_rec = (UNITS / 4) * UNITS;   // 16384 quad-slots
    int n_sen = (IN_DIM / 4) * UNITS;  // 8192
    prep_quad_kernel<<<(n_rec + 255) / 256, 256, 0, stream>>>(
        mu, sigma, W, erev, rA, rB, rW, rE, n_rec);
    prep_quad_kernel<<<(n_sen + 255) / 256, 256, 0, stream>>>(
        sensory_mu, sensory_sig, sensory_W, sensory_erev, sA, sB, sW, sE, n_sen);

    ltc_kernel<<<BATCH / RB, 512, 0, stream>>>(
        rA, rB, rW, rE, sA, sB, sW, sE,
        inputs, state, vleak, gleak, cm_t, out);
}

// Round 8
// 500.601 us; speedup vs baseline: 1.1738x; 1.1738x over previous
//
#include <hip/hip_runtime.h>
#include <hip/hip_fp16.h>

#define NFOLDS 12
#define EPS 1e-8f
#define BATCH 2048
#define IN_DIM 128
#define UNITS 256
#define RB 4
#define LOG2E 1.44269504088896340736f

#if __has_builtin(__builtin_amdgcn_rcpf)
#define RCPF(x) __builtin_amdgcn_rcpf(x)
#else
#define RCPF(x) (1.0f / (x))
#endif

typedef _Float16 v2h __attribute__((ext_vector_type(2)));

// ---- packed f16 / 16-bit-int ops, all single-VGPR unsigned carriers ----
__device__ __forceinline__ unsigned pk_fma_h(unsigned a, unsigned b, unsigned c) {
    unsigned d;
    asm("v_pk_fma_f16 %0, %1, %2, %3" : "=v"(d) : "v"(a), "v"(b), "v"(c));
    return d;
}
__device__ __forceinline__ unsigned pk_add_h(unsigned a, unsigned b) {
    unsigned d;
    asm("v_pk_add_f16 %0, %1, %2" : "=v"(d) : "v"(a), "v"(b));
    return d;
}
__device__ __forceinline__ unsigned pk_max_h(unsigned a, unsigned b) {
    unsigned d;
    asm("v_pk_max_f16 %0, %1, %2" : "=v"(d) : "v"(a), "v"(b));
    return d;
}
__device__ __forceinline__ unsigned pk_min_h(unsigned a, unsigned b) {
    unsigned d;
    asm("v_pk_min_f16 %0, %1, %2" : "=v"(d) : "v"(a), "v"(b));
    return d;
}
__device__ __forceinline__ unsigned pksub16(unsigned a, unsigned b) {
    unsigned d;
    asm("v_pk_sub_u16 %0, %1, %2" : "=v"(d) : "v"(a), "v"(b));
    return d;
}
__device__ __forceinline__ unsigned pkshl16(unsigned sh, unsigned a) {
    unsigned d;
    asm("v_pk_lshlrev_b16 %0, %1, %2" : "=v"(d) : "v"(sh), "v"(a));
    return d;
}

struct KC {
    unsigned c1536, negc1536, none, one, nc1, nc2, nc3, hi12, lo12;
    unsigned k497, sh10, rmagic;
};

// One synapse PAIR, entirely packed f16 (VOP3P), f32 accumulate via dot2:
//   t = a*v + b (log2-domain sigmoid arg), clamp [-12,12]
//   z = t + 1536 -> RTNE integer n in mantissa (f16 magic, ULP=1 at 2^10)
//   f = t - n (exact) ; -2^f via negated deg-3 poly
//   2^n bits = (bits(z) - 497) << 10   (n+15 in [3,27], no overflow)
//   nA = -(1 + 2^t) ; r = 1/A via magic seed + 2 packed Newton
//   red += dot2(w2, r) ; num += dot2(we2, r)
__device__ __forceinline__ void chain(const uint4 q, unsigned v2u, const KC& K,
                                      float& red, float& num) {
    unsigned t = pk_fma_h(q.x, v2u, q.y);
    t = pk_max_h(t, K.lo12);
    t = pk_min_h(t, K.hi12);
    unsigned z = pk_add_h(t, K.c1536);
    unsigned n = pk_add_h(z, K.negc1536);   // n as f16 (exact, Sterbenz)
    unsigned f = pk_fma_h(n, K.none, t);    // f = t - n in [-0.5, 0.5]
    unsigned p = pk_fma_h(K.nc3, f, K.nc2);
    p = pk_fma_h(p, f, K.nc1);
    p = pk_fma_h(p, f, K.none);             // p = -2^f
    unsigned s = pkshl16(K.sh10, pksub16(z, K.k497));  // bits of 2^n
    unsigned nA = pk_fma_h(p, s, K.none);   // -(1 + 2^t)
    unsigned r = pksub16(K.rmagic, nA);     // seed of 1/A (±7% rel)
    unsigned e = pk_fma_h(nA, r, K.one);    // 1 - A*r
    r = pk_fma_h(r, e, r);
    e = pk_fma_h(nA, r, K.one);
    r = pk_fma_h(r, e, r);                  // 1/A = sigmoid pair
    v2h rr = __builtin_bit_cast(v2h, r);
    red = __builtin_amdgcn_fdot2(__builtin_bit_cast(v2h, q.z), rr, red, false);
    num = __builtin_amdgcn_fdot2(__builtin_bit_cast(v2h, q.w), rr, num, false);
}

// Pack per j-pair p (rows 2p, 2p+1), col u: {a2, b2, w2, we2} f16 pairs:
//   a = -sigma*log2e, b = sigma*mu*log2e, w = W, we = W*erev
__global__ void prep_h2_kernel(const float* __restrict__ mu,
                               const float* __restrict__ sigma,
                               const float* __restrict__ W,
                               const float* __restrict__ erev,
                               uint4* __restrict__ out, int n) {
    int i = blockIdx.x * blockDim.x + threadIdx.x;  // i = p*UNITS + u
    if (i < n) {
        int p = i >> 8;
        int u = i & (UNITS - 1);
        int i0 = (2 * p) * UNITS + u;
        int i1 = i0 + UNITS;
        float A0 = sigma[i0] * LOG2E, A1 = sigma[i1] * LOG2E;
        __half2 a2, b2, w2, e2;
        a2.x = __float2half(-A0);              a2.y = __float2half(-A1);
        b2.x = __float2half(A0 * mu[i0]);      b2.y = __float2half(A1 * mu[i1]);
        w2.x = __float2half(W[i0]);            w2.y = __float2half(W[i1]);
        e2.x = __float2half(W[i0] * erev[i0]); e2.y = __float2half(W[i1] * erev[i1]);
        uint4 o;
        o.x = __builtin_bit_cast(unsigned, a2);
        o.y = __builtin_bit_cast(unsigned, b2);
        o.z = __builtin_bit_cast(unsigned, w2);
        o.w = __builtin_bit_cast(unsigned, e2);
        out[i] = o;
    }
}

// Block: 512 threads = (u: 0..255) x (h: reduction half 0..1). RB=4 rows.
__global__ __launch_bounds__(512, 4) void ltc_kernel(
    const uint4* __restrict__ rq,     // [UNITS/2][UNITS] recurrent pair params
    const uint4* __restrict__ sq,     // [IN_DIM/2][UNITS] sensory pair params
    const float* __restrict__ inputs, // [BATCH][IN_DIM]
    const float* __restrict__ state,  // [BATCH][UNITS]
    const float* __restrict__ vleak,
    const float* __restrict__ gleak,
    const float* __restrict__ cm_t,
    float* __restrict__ out)          // [BATCH][UNITS]
{
    const int tid = threadIdx.x;
    const int u = tid & (UNITS - 1);
    const int h = tid >> 8;
    const int b0 = blockIdx.x * RB;

    KC K;
    K.c1536    = __builtin_bit_cast(unsigned, __float2half2_rn(1536.0f));
    K.negc1536 = __builtin_bit_cast(unsigned, __float2half2_rn(-1536.0f));
    K.none     = __builtin_bit_cast(unsigned, __float2half2_rn(-1.0f));
    K.one      = __builtin_bit_cast(unsigned, __float2half2_rn(1.0f));
    K.nc1      = __builtin_bit_cast(unsigned, __float2half2_rn(-0.6931472f));
    K.nc2      = __builtin_bit_cast(unsigned, __float2half2_rn(-0.2401397f));
    K.nc3      = __builtin_bit_cast(unsigned, __float2half2_rn(-0.0558282f));
    K.hi12     = __builtin_bit_cast(unsigned, __float2half2_rn(12.0f));
    K.lo12     = __builtin_bit_cast(unsigned, __float2half2_rn(-12.0f));
    K.k497  = 0x01F101F1u;
    K.sh10  = 0x000A000Au;
    K.rmagic = 0xF7B6F7B6u;

    __shared__ unsigned vp_sh[RB][UNITS / 2];   // packed f16 v pairs
    __shared__ unsigned in_sh[RB][IN_DIM / 2];  // packed f16 input pairs
    __shared__ float nb_sh[RB][UNITS];   // glvl + snum
    __shared__ float db_sh[RB][UNITS];   // cm + gl + sden + EPS
    __shared__ float cm_sh[UNITS];
    __shared__ float pred[2][RB][UNITS];
    __shared__ float pnum[2][RB][UNITS];

    // ---- stage: pack v rows and input rows to f16 pairs ----
    if (h == 0) {
        #pragma unroll
        for (int k = u; k < RB * (UNITS / 2); k += UNITS) {
            int rb = k >> 7, p = k & 127;
            const float* src = state + (b0 + rb) * UNITS + 2 * p;
            __half2 hh; hh.x = __float2half(src[0]); hh.y = __float2half(src[1]);
            vp_sh[rb][p] = __builtin_bit_cast(unsigned, hh);
        }
        cm_sh[u] = cm_t[u];
    } else {
        int rb = u >> 6, p = u & 63;     // 256 slots, one per thread
        const float* src = inputs + (b0 + rb) * IN_DIM + 2 * p;
        __half2 hh; hh.x = __float2half(src[0]); hh.y = __float2half(src[1]);
        in_sh[rb][p] = __builtin_bit_cast(unsigned, hh);
    }
    float vfull[2];   // exact f32 v for this thread's rows (h, h+2)
    #pragma unroll
    for (int k = 0; k < 2; ++k)
        vfull[k] = state[(b0 + h + 2 * k) * UNITS + u];
    __syncthreads();

    // ---- sensory path: half h covers 32 of 64 i-pairs ----
    {
        float sden[RB] = {0.f, 0.f, 0.f, 0.f};
        float snum[RB] = {0.f, 0.f, 0.f, 0.f};
        for (int pr = h * 32; pr < h * 32 + 32; pr += 2) {
            uint4 q0 = sq[(pr + 0) * UNITS + u];
            uint4 q1 = sq[(pr + 1) * UNITS + u];
            #pragma unroll
            for (int rb = 0; rb < RB; ++rb) {
                uint2 vv = *reinterpret_cast<const uint2*>(&in_sh[rb][pr]);
                chain(q0, vv.x, K, sden[rb], snum[rb]);
                chain(q1, vv.y, K, sden[rb], snum[rb]);
            }
        }
        #pragma unroll
        for (int rb = 0; rb < RB; ++rb) {
            pred[h][rb][u] = sden[rb];
            pnum[h][rb][u] = snum[rb];
        }
    }
    __syncthreads();

    #pragma unroll
    for (int k = 0; k < 2; ++k) {
        const int rb = h + 2 * k;
        float gl = gleak[u];
        float sd = pred[0][rb][u] + pred[1][rb][u];
        float sn = pnum[0][rb][u] + pnum[1][rb][u];
        db_sh[rb][u] = cm_sh[u] + gl + sd + EPS;
        nb_sh[rb][u] = fmaf(gl, vleak[u], sn);
    }
    __syncthreads();

    // ---- 12 folds: half h covers 64 of 128 j-pairs ----
    for (int f = 0; f < NFOLDS; ++f) {
        float wred[RB] = {0.f, 0.f, 0.f, 0.f};
        float wnum[RB] = {0.f, 0.f, 0.f, 0.f};
        for (int pr = h * 64; pr < h * 64 + 64; pr += 2) {
            uint4 q0 = rq[(pr + 0) * UNITS + u];
            uint4 q1 = rq[(pr + 1) * UNITS + u];
            #pragma unroll
            for (int rb = 0; rb < RB; ++rb) {
                uint2 vv = *reinterpret_cast<const uint2*>(&vp_sh[rb][pr]);
                chain(q0, vv.x, K, wred[rb], wnum[rb]);
                chain(q1, vv.y, K, wred[rb], wnum[rb]);
            }
        }
        #pragma unroll
        for (int rb = 0; rb < RB; ++rb) {
            pred[h][rb][u] = wred[rb];
            pnum[h][rb][u] = wnum[rb];
        }
        __syncthreads();

        // epilogue: rows h, h+2 for this thread; pack new v via lane pairing
        float vn[2];
        #pragma unroll
        for (int k = 0; k < 2; ++k) {
            const int rb = h + 2 * k;
            float wr = pred[0][rb][u] + pred[1][rb][u];
            float wn = pnum[0][rb][u] + pnum[1][rb][u];
            float num = fmaf(cm_sh[u], vfull[k], nb_sh[rb][u]) + wn;
            float den = db_sh[rb][u] + wr;
            vn[k] = num * RCPF(den);
            vfull[k] = vn[k];
            if (f == NFOLDS - 1)
                out[(b0 + rb) * UNITS + u] = vn[k];
        }
        float o0 = __shfl_xor(vn[0], 1);
        float o1 = __shfl_xor(vn[1], 1);
        if (!(u & 1)) {
            __half2 p0; p0.x = __float2half(vn[0]); p0.y = __float2half(o0);
            __half2 p1; p1.x = __float2half(vn[1]); p1.y = __float2half(o1);
            vp_sh[h][u >> 1]     = __builtin_bit_cast(unsigned, p0);
            vp_sh[h + 2][u >> 1] = __builtin_bit_cast(unsigned, p1);
        }
        __syncthreads();
    }
}

extern "C" void kernel_launch(void* const* d_in, const int* in_sizes, int n_in,
                              void* d_out, int out_size, void* d_ws, size_t ws_size,
                              hipStream_t stream) {
    const float* inputs       = (const float*)d_in[0];
    const float* state        = (const float*)d_in[1];
    const float* sensory_mu   = (const float*)d_in[2];
    const float* sensory_sig  = (const float*)d_in[3];
    const float* sensory_W    = (const float*)d_in[4];
    const float* sensory_erev = (const float*)d_in[5];
    const float* mu           = (const float*)d_in[6];
    const float* sigma        = (const float*)d_in[7];
    const float* W            = (const float*)d_in[8];
    const float* erev         = (const float*)d_in[9];
    const float* vleak        = (const float*)d_in[10];
    const float* gleak        = (const float*)d_in[11];
    const float* cm_t         = (const float*)d_in[12];
    float* out = (float*)d_out;

    // workspace: rq (128x256 uint4 = 512KB) | sq (64x256 uint4 = 256KB)
    uint4* rq = (uint4*)d_ws;
    uint4* sq = rq + (UNITS / 2) * UNITS;

    int n_rec = (UNITS / 2) * UNITS;   // 32768 pair-slots
    int n_sen = (IN_DIM / 2) * UNITS;  // 16384
    prep_h2_kernel<<<(n_rec + 255) / 256, 256, 0, stream>>>(
        mu, sigma, W, erev, rq, n_rec);
    prep_h2_kernel<<<(n_sen + 255) / 256, 256, 0, stream>>>(
        sensory_mu, sensory_sig, sensory_W, sensory_erev, sq, n_sen);

    ltc_kernel<<<BATCH / RB, 512, 0, stream>>>(rq, sq, inputs, state,
                                               vleak, gleak, cm_t, out);
}

// Round 9
// 336.427 us; speedup vs baseline: 1.7466x; 1.4880x over previous
//
#include <hip/hip_runtime.h>

#define NFOLDS 12
#define EPS 1e-8f
#define BATCH 2048
#define IN_DIM 128
#define UNITS 256
#define RB 4
#define LOG2E 1.44269504088896340736f
#define VCLAMP 4.5f

#if __has_builtin(__builtin_amdgcn_rcpf)
#define RCPF(x) __builtin_amdgcn_rcpf(x)
#else
#define RCPF(x) (1.0f / (x))
#endif

// Schraudolph exp2: 2^t ~= bitcast_f32((int)(t*2^23 + (127*2^23 - D)))
// D = 361167 balances the mantissa-chord error to +-3.0% rel.
// Scale+bias are folded into the packed params -> ONE fma per synapse.
#define SCHRA_BIAS 1064992049.0f   // 127*2^23 - 361167

// One synapse pair, no transcendental exp (pair shares one exact hw rcp):
//   z = a2p*v + b2p    (a2p = -sigma*log2e*2^23 ; b2p = sig*mu*log2e*2^23+BIAS)
//   e = bitcast((int)z) = 2^t ; A = 1+e ; g = 1/A via shared rcp
//   red += W*g ; num += W*erev*g
__device__ __forceinline__ void syn_pair(const float4 qa, const float4 qb,
                                         const float v0, const float v1,
                                         float& red, float& num) {
    float z0 = fmaf(qa.x, v0, qa.z);
    float z1 = fmaf(qa.y, v1, qa.w);
    float e0 = __int_as_float((int)z0);
    float e1 = __int_as_float((int)z1);
    float A0 = 1.0f + e0;
    float A1 = 1.0f + e1;
    float R = RCPF(A0 * A1);           // exact hw rcp, shared by the pair
    float g0 = R * A1;
    float g1 = R * A0;
    red = fmaf(qb.x, g0, red);
    red = fmaf(qb.y, g1, red);
    num = fmaf(qb.z, g0, num);
    num = fmaf(qb.w, g1, num);
}

// Pair-packed params: for row-pair p (rows 2p,2p+1), col u:
//   outA = {-A0*2^23, -A1*2^23, A0*mu0*2^23+BIAS, A1*mu1*2^23+BIAS}
//   outB = {W0, W1, W0*erev0, W1*erev1}     (A = sigma*log2e)
__global__ void prep_pair_kernel(const float* __restrict__ mu,
                                 const float* __restrict__ sigma,
                                 const float* __restrict__ W,
                                 const float* __restrict__ erev,
                                 float4* __restrict__ outA,
                                 float4* __restrict__ outB, int n) {
    int i = blockIdx.x * blockDim.x + threadIdx.x;  // i = p*UNITS + u
    if (i < n) {
        int p = i >> 8;
        int u = i & (UNITS - 1);
        int i0 = (2 * p) * UNITS + u;
        int i1 = i0 + UNITS;
        const float S23 = 8388608.0f;  // 2^23
        float A0 = sigma[i0] * LOG2E, A1 = sigma[i1] * LOG2E;
        outA[i] = make_float4(-A0 * S23, -A1 * S23,
                              fmaf(A0 * mu[i0], S23, SCHRA_BIAS),
                              fmaf(A1 * mu[i1], S23, SCHRA_BIAS));
        float w0 = W[i0], w1 = W[i1];
        outB[i] = make_float4(w0, w1, w0 * erev[i0], w1 * erev[i1]);
    }
}

// Block: 512 threads = (u: 0..255) x (h: reduction half 0..1). RB=4 rows.
__global__ __launch_bounds__(512, 4) void ltc_kernel(
    const float4* __restrict__ rpA,   // [UNITS/2][UNITS] recurrent pair params
    const float4* __restrict__ rpB,
    const float4* __restrict__ spA,   // [IN_DIM/2][UNITS] sensory pair params
    const float4* __restrict__ spB,
    const float* __restrict__ inputs, // [BATCH][IN_DIM]
    const float* __restrict__ state,  // [BATCH][UNITS]
    const float* __restrict__ vleak,
    const float* __restrict__ gleak,
    const float* __restrict__ cm_t,
    float* __restrict__ out)          // [BATCH][UNITS]
{
    const int tid = threadIdx.x;
    const int u = tid & (UNITS - 1);
    const int h = tid >> 8;
    const int b0 = blockIdx.x * RB;

    __shared__ __align__(16) float v_sh[RB][UNITS];
    __shared__ __align__(16) float in_sh[RB][IN_DIM];
    __shared__ float nb_sh[RB][UNITS];   // glvl + snum
    __shared__ float db_sh[RB][UNITS];   // cm + gl + sden + EPS
    __shared__ float cm_sh[UNITS];
    __shared__ float pred[2][RB][UNITS];
    __shared__ float pnum[2][RB][UNITS];

    // ---- stage rows. v_sh holds CLAMPED v (synapse input only: bounds
    //      |t| <= 61.2 so the Schraudolph int stays in [65*2^23, 189*2^23]).
    //      Unclamped v kept in registers for the cm*v term. ----
    if (h == 0) {
        #pragma unroll
        for (int rb = 0; rb < RB; ++rb) {
            float s = state[(b0 + rb) * UNITS + u];
            v_sh[rb][u] = fminf(fmaxf(s, -VCLAMP), VCLAMP);
        }
        cm_sh[u] = cm_t[u];
    } else {
        #pragma unroll
        for (int k = u; k < RB * IN_DIM; k += UNITS) {
            int rb = k >> 7;
            int i  = k & (IN_DIM - 1);
            float x = inputs[(b0 + rb) * IN_DIM + i];
            in_sh[rb][i] = fminf(fmaxf(x, -VCLAMP), VCLAMP);
        }
    }
    float vfull[2];   // exact f32 v for this thread's rows (h, h+2)
    #pragma unroll
    for (int k = 0; k < 2; ++k)
        vfull[k] = state[(b0 + h + 2 * k) * UNITS + u];
    __syncthreads();

    // ---- sensory path: half h sums i in [h*64, h*64+64) = 32 pairs ----
    {
        float sden[RB] = {0.f, 0.f, 0.f, 0.f};
        float snum[RB] = {0.f, 0.f, 0.f, 0.f};
        const int ibase = h * (IN_DIM / 2);
        for (int ic = 0; ic < IN_DIM / 2; ic += 4) {
            const int i = ibase + ic;
            const int pr = i >> 1;
            float4 qa0 = spA[(pr + 0) * UNITS + u];
            float4 qb0 = spB[(pr + 0) * UNITS + u];
            float4 qa1 = spA[(pr + 1) * UNITS + u];
            float4 qb1 = spB[(pr + 1) * UNITS + u];
            #pragma unroll
            for (int rb = 0; rb < RB; ++rb) {
                float4 x4 = *reinterpret_cast<const float4*>(&in_sh[rb][i]);
                syn_pair(qa0, qb0, x4.x, x4.y, sden[rb], snum[rb]);
                syn_pair(qa1, qb1, x4.z, x4.w, sden[rb], snum[rb]);
            }
        }
        #pragma unroll
        for (int rb = 0; rb < RB; ++rb) {
            pred[h][rb][u] = sden[rb];
            pnum[h][rb][u] = snum[rb];
        }
    }
    __syncthreads();

    // combine sensory partials into per-(rb,u) bases
    #pragma unroll
    for (int k = 0; k < 2; ++k) {
        const int rb = h + 2 * k;
        float gl = gleak[u];
        float sd = pred[0][rb][u] + pred[1][rb][u];
        float sn = pnum[0][rb][u] + pnum[1][rb][u];
        db_sh[rb][u] = cm_sh[u] + gl + sd + EPS;
        nb_sh[rb][u] = fmaf(gl, vleak[u], sn);
    }
    __syncthreads();

    // ---- 12 folds: half h reduces j in [h*128, h*128+128) = 64 pairs ----
    for (int f = 0; f < NFOLDS; ++f) {
        float wred[RB] = {0.f, 0.f, 0.f, 0.f};
        float wnum[RB] = {0.f, 0.f, 0.f, 0.f};
        const int jbase = h * (UNITS / 2);
        for (int jc = 0; jc < UNITS / 2; jc += 4) {
            const int j = jbase + jc;
            const int pr = j >> 1;
            float4 qa0 = rpA[(pr + 0) * UNITS + u];
            float4 qb0 = rpB[(pr + 0) * UNITS + u];
            float4 qa1 = rpA[(pr + 1) * UNITS + u];
            float4 qb1 = rpB[(pr + 1) * UNITS + u];
            #pragma unroll
            for (int rb = 0; rb < RB; ++rb) {
                float4 v4 = *reinterpret_cast<const float4*>(&v_sh[rb][j]);
                syn_pair(qa0, qb0, v4.x, v4.y, wred[rb], wnum[rb]);
                syn_pair(qa1, qb1, v4.z, v4.w, wred[rb], wnum[rb]);
            }
        }
        #pragma unroll
        for (int rb = 0; rb < RB; ++rb) {
            pred[h][rb][u] = wred[rb];
            pnum[h][rb][u] = wnum[rb];
        }
        __syncthreads();

        #pragma unroll
        for (int k = 0; k < 2; ++k) {
            const int rb = h + 2 * k;
            float wr = pred[0][rb][u] + pred[1][rb][u];
            float wn = pnum[0][rb][u] + pnum[1][rb][u];
            float num = fmaf(cm_sh[u], vfull[k], nb_sh[rb][u]) + wn;
            float den = db_sh[rb][u] + wr;
            float vn = num * RCPF(den);
            vfull[k] = vn;                                   // exact v for cm*v
            v_sh[rb][u] = fminf(fmaxf(vn, -VCLAMP), VCLAMP); // synapse input
            if (f == NFOLDS - 1)
                out[(b0 + rb) * UNITS + u] = vn;
        }
        __syncthreads();
    }
}

extern "C" void kernel_launch(void* const* d_in, const int* in_sizes, int n_in,
                              void* d_out, int out_size, void* d_ws, size_t ws_size,
                              hipStream_t stream) {
    const float* inputs       = (const float*)d_in[0];
    const float* state        = (const float*)d_in[1];
    const float* sensory_mu   = (const float*)d_in[2];
    const float* sensory_sig  = (const float*)d_in[3];
    const float* sensory_W    = (const float*)d_in[4];
    const float* sensory_erev = (const float*)d_in[5];
    const float* mu           = (const float*)d_in[6];
    const float* sigma        = (const float*)d_in[7];
    const float* W            = (const float*)d_in[8];
    const float* erev         = (const float*)d_in[9];
    const float* vleak        = (const float*)d_in[10];
    const float* gleak        = (const float*)d_in[11];
    const float* cm_t         = (const float*)d_in[12];
    float* out = (float*)d_out;

    // workspace: rpA | rpB | spA | spB  (pair-packed float4 arrays, 1.5 MB)
    float4* rpA = (float4*)d_ws;
    float4* rpB = rpA + (UNITS / 2) * UNITS;
    float4* spA = rpB + (UNITS / 2) * UNITS;
    float4* spB = spA + (IN_DIM / 2) * UNITS;

    int n_rec = (UNITS / 2) * UNITS;   // 32768 pair-slots
    int n_sen = (IN_DIM / 2) * UNITS;  // 16384
    prep_pair_kernel<<<(n_rec + 255) / 256, 256, 0, stream>>>(
        mu, sigma, W, erev, rpA, rpB, n_rec);
    prep_pair_kernel<<<(n_sen + 255) / 256, 256, 0, stream>>>(
        sensory_mu, sensory_sig, sensory_W, sensory_erev, spA, spB, n_sen);

    ltc_kernel<<<BATCH / RB, 512, 0, stream>>>(rpA, rpB, spA, spB, inputs, state,
                                               vleak, gleak, cm_t, out);
}

// Round 10
// 335.461 us; speedup vs baseline: 1.7517x; 1.0029x over previous
//
#include <hip/hip_runtime.h>

#define NFOLDS 12
#define EPS 1e-8f
#define BATCH 2048
#define IN_DIM 128
#define UNITS 256
#define RB 4
#define LOG2E 1.44269504088896340736f
#define VCLAMP 4.5f

#if __has_builtin(__builtin_amdgcn_rcpf)
#define RCPF(x) __builtin_amdgcn_rcpf(x)
#else
#define RCPF(x) (1.0f / (x))
#endif

// Exponent-shift Schraudolph:
//   z = a'*v + b''  with a' = -sigma*log2e*2^15,
//   b'' = sigma*mu*log2e*2^15 + (127*2^23 - D)/256 + 2^23   (D = 361167)
//   z stays in [2^23, 2^24) -> mantissa holds the integer exactly, and
//   bits(z) << 8 == (int)(t*2^23 + 127*2^23 - D)  (0x4B000000<<8 wraps to 0)
//   -> e = bitcast(bits(z)<<8) = 2^t with +-3% balanced sawtooth error.
// B_CONST = (127*2^23 - 361167)/256 + 2^23
#define B_CONST 12549514.44140625f
#define S15 32768.0f

// One synapse, 8 full-rate VALU ops, no transcendentals:
//   z -> e = 2^t -> A = 1+e -> r = 1/A via magic seed + 1 Newton
//   red += W*r ; num += W*erev*r
__device__ __forceinline__ void syn1(const float4 q, const float v,
                                     float& red, float& num) {
    float z = fmaf(q.x, v, q.y);
    float e = __uint_as_float(__float_as_uint(z) << 8);
    float A = 1.0f + e;
    float r = __uint_as_float(0x7EF311C7u - __float_as_uint(A));  // ~5% seed
    float h = fmaf(-A, r, 1.0f);
    r = fmaf(r, h, r);                 // 1 Newton: rel err <= 0.26%
    red = fmaf(q.z, r, red);
    num = fmaf(q.w, r, num);
}

// Per (j,u): {a', b'', W, W*erev}
__global__ void prep_kernel(const float* __restrict__ mu,
                            const float* __restrict__ sigma,
                            const float* __restrict__ W,
                            const float* __restrict__ erev,
                            float4* __restrict__ out, int n) {
    int i = blockIdx.x * blockDim.x + threadIdx.x;
    if (i < n) {
        float As = sigma[i] * LOG2E;
        float w = W[i];
        out[i] = make_float4(-As * S15,
                             fmaf(As * mu[i], S15, B_CONST),
                             w, w * erev[i]);
    }
}

// Block: 512 threads = (u: 0..255) x (h: reduction half 0..1). RB=4 rows.
__global__ __launch_bounds__(512, 4) void ltc_kernel(
    const float4* __restrict__ rp,    // [UNITS][UNITS] recurrent params
    const float4* __restrict__ sp,    // [IN_DIM][UNITS] sensory params
    const float* __restrict__ inputs, // [BATCH][IN_DIM]
    const float* __restrict__ state,  // [BATCH][UNITS]
    const float* __restrict__ vleak,
    const float* __restrict__ gleak,
    const float* __restrict__ cm_t,
    float* __restrict__ out)          // [BATCH][UNITS]
{
    const int tid = threadIdx.x;
    const int u = tid & (UNITS - 1);
    const int h = tid >> 8;
    const int b0 = blockIdx.x * RB;

    __shared__ __align__(16) float v_sh[RB][UNITS];
    __shared__ __align__(16) float in_sh[RB][IN_DIM];
    __shared__ float nb_sh[RB][UNITS];   // glvl + snum
    __shared__ float db_sh[RB][UNITS];   // cm + gl + sden + EPS
    __shared__ float cm_sh[UNITS];
    __shared__ float pred[2][RB][UNITS];
    __shared__ float pnum[2][RB][UNITS];

    // ---- stage rows. v_sh holds CLAMPED v (synapse input only: bounds
    //      |t| <= 61.2 so the shifted mantissa stays in [0, 2^23)).
    //      Unclamped v kept in registers for the cm*v term. ----
    if (h == 0) {
        #pragma unroll
        for (int rb = 0; rb < RB; ++rb) {
            float s = state[(b0 + rb) * UNITS + u];
            v_sh[rb][u] = fminf(fmaxf(s, -VCLAMP), VCLAMP);
        }
        cm_sh[u] = cm_t[u];
    } else {
        #pragma unroll
        for (int k = u; k < RB * IN_DIM; k += UNITS) {
            int rb = k >> 7;
            int i  = k & (IN_DIM - 1);
            float x = inputs[(b0 + rb) * IN_DIM + i];
            in_sh[rb][i] = fminf(fmaxf(x, -VCLAMP), VCLAMP);
        }
    }
    float vfull[2];   // exact f32 v for this thread's rows (h, h+2)
    #pragma unroll
    for (int k = 0; k < 2; ++k)
        vfull[k] = state[(b0 + h + 2 * k) * UNITS + u];
    __syncthreads();

    // ---- sensory path: half h sums i in [h*64, h*64+64) ----
    {
        float sden[RB] = {0.f, 0.f, 0.f, 0.f};
        float snum[RB] = {0.f, 0.f, 0.f, 0.f};
        const int ibase = h * (IN_DIM / 2);
        for (int ic = 0; ic < IN_DIM / 2; ic += 4) {
            const int i = ibase + ic;
            float4 q0 = sp[(i + 0) * UNITS + u];
            float4 q1 = sp[(i + 1) * UNITS + u];
            float4 q2 = sp[(i + 2) * UNITS + u];
            float4 q3 = sp[(i + 3) * UNITS + u];
            #pragma unroll
            for (int rb = 0; rb < RB; ++rb) {
                float4 x4 = *reinterpret_cast<const float4*>(&in_sh[rb][i]);
                syn1(q0, x4.x, sden[rb], snum[rb]);
                syn1(q1, x4.y, sden[rb], snum[rb]);
                syn1(q2, x4.z, sden[rb], snum[rb]);
                syn1(q3, x4.w, sden[rb], snum[rb]);
            }
        }
        #pragma unroll
        for (int rb = 0; rb < RB; ++rb) {
            pred[h][rb][u] = sden[rb];
            pnum[h][rb][u] = snum[rb];
        }
    }
    __syncthreads();

    // combine sensory partials into per-(rb,u) bases
    #pragma unroll
    for (int k = 0; k < 2; ++k) {
        const int rb = h + 2 * k;
        float gl = gleak[u];
        float sd = pred[0][rb][u] + pred[1][rb][u];
        float sn = pnum[0][rb][u] + pnum[1][rb][u];
        db_sh[rb][u] = cm_sh[u] + gl + sd + EPS;
        nb_sh[rb][u] = fmaf(gl, vleak[u], sn);
    }
    __syncthreads();

    // ---- 12 folds: half h reduces j in [h*128, h*128+128) ----
    for (int f = 0; f < NFOLDS; ++f) {
        float wred[RB] = {0.f, 0.f, 0.f, 0.f};
        float wnum[RB] = {0.f, 0.f, 0.f, 0.f};
        const int jbase = h * (UNITS / 2);
        for (int jc = 0; jc < UNITS / 2; jc += 4) {
            const int j = jbase + jc;
            float4 q0 = rp[(j + 0) * UNITS + u];
            float4 q1 = rp[(j + 1) * UNITS + u];
            float4 q2 = rp[(j + 2) * UNITS + u];
            float4 q3 = rp[(j + 3) * UNITS + u];
            #pragma unroll
            for (int rb = 0; rb < RB; ++rb) {
                float4 v4 = *reinterpret_cast<const float4*>(&v_sh[rb][j]);
                syn1(q0, v4.x, wred[rb], wnum[rb]);
                syn1(q1, v4.y, wred[rb], wnum[rb]);
                syn1(q2, v4.z, wred[rb], wnum[rb]);
                syn1(q3, v4.w, wred[rb], wnum[rb]);
            }
        }
        #pragma unroll
        for (int rb = 0; rb < RB; ++rb) {
            pred[h][rb][u] = wred[rb];
            pnum[h][rb][u] = wnum[rb];
        }
        __syncthreads();

        #pragma unroll
        for (int k = 0; k < 2; ++k) {
            const int rb = h + 2 * k;
            float wr = pred[0][rb][u] + pred[1][rb][u];
            float wn = pnum[0][rb][u] + pnum[1][rb][u];
            float num = fmaf(cm_sh[u], vfull[k], nb_sh[rb][u]) + wn;
            float den = db_sh[rb][u] + wr;
            float vn = num * RCPF(den);
            vfull[k] = vn;                                   // exact v for cm*v
            v_sh[rb][u] = fminf(fmaxf(vn, -VCLAMP), VCLAMP); // synapse input
            if (f == NFOLDS - 1)
                out[(b0 + rb) * UNITS + u] = vn;
        }
        __syncthreads();
    }
}

extern "C" void kernel_launch(void* const* d_in, const int* in_sizes, int n_in,
                              void* d_out, int out_size, void* d_ws, size_t ws_size,
                              hipStream_t stream) {
    const float* inputs       = (const float*)d_in[0];
    const float* state        = (const float*)d_in[1];
    const float* sensory_mu   = (const float*)d_in[2];
    const float* sensory_sig  = (const float*)d_in[3];
    const float* sensory_W    = (const float*)d_in[4];
    const float* sensory_erev = (const float*)d_in[5];
    const float* mu           = (const float*)d_in[6];
    const float* sigma        = (const float*)d_in[7];
    const float* W            = (const float*)d_in[8];
    const float* erev         = (const float*)d_in[9];
    const float* vleak        = (const float*)d_in[10];
    const float* gleak        = (const float*)d_in[11];
    const float* cm_t         = (const float*)d_in[12];
    float* out = (float*)d_out;

    // workspace: rp (256x256 float4 = 1MB) | sp (128x256 float4 = 512KB)
    float4* rp = (float4*)d_ws;
    float4* sp = rp + UNITS * UNITS;

    int n_rec = UNITS * UNITS;   // 65536
    int n_sen = IN_DIM * UNITS;  // 32768
    prep_kernel<<<(n_rec + 255) / 256, 256, 0, stream>>>(mu, sigma, W, erev, rp, n_rec);
    prep_kernel<<<(n_sen + 255) / 256, 256, 0, stream>>>(
        sensory_mu, sensory_sig, sensory_W, sensory_erev, sp, n_sen);

    ltc_kernel<<<BATCH / RB, 512, 0, stream>>>(rp, sp, inputs, state,
                                               vleak, gleak, cm_t, out);
}

// Round 11
// 330.292 us; speedup vs baseline: 1.7791x; 1.0156x over previous
//
#include <hip/hip_runtime.h>

#define NFOLDS 12
#define EPS 1e-8f
#define BATCH 2048
#define IN_DIM 128
#define UNITS 256
#define RB 4
#define NH 4
#define LOG2E 1.44269504088896340736f
#define VCLAMP 4.5f

#if __has_builtin(__builtin_amdgcn_rcpf)
#define RCPF(x) __builtin_amdgcn_rcpf(x)
#else
#define RCPF(x) (1.0f / (x))
#endif

// Exponent-shift Schraudolph (proven round 10, absmax 5.9e-3):
//   z = a'*v + b''  with a' = -sigma*log2e*2^15,
//   b'' = sigma*mu*log2e*2^15 + (127*2^23 - D)/256 + 2^23   (D = 361167)
//   z in [2^23, 2^24) -> bits(z)<<8 = Schraudolph int of 2^t (+-3% sawtooth)
#define B_CONST 12549514.44140625f
#define S15 32768.0f

// One synapse, 8 full-rate VALU ops, no transcendentals.
__device__ __forceinline__ void syn1(const float4 q, const float v,
                                     float& red, float& num) {
    float z = fmaf(q.x, v, q.y);
    float e = __uint_as_float(__float_as_uint(z) << 8);
    float A = 1.0f + e;
    float r = __uint_as_float(0x7EF311C7u - __float_as_uint(A));  // ~5% seed
    float h = fmaf(-A, r, 1.0f);
    r = fmaf(r, h, r);                 // 1 Newton: rel err <= 0.26%
    red = fmaf(q.z, r, red);
    num = fmaf(q.w, r, num);
}

// Per (j,u): {a', b'', W, W*erev}
__global__ void prep_kernel(const float* __restrict__ mu,
                            const float* __restrict__ sigma,
                            const float* __restrict__ W,
                            const float* __restrict__ erev,
                            float4* __restrict__ out, int n) {
    int i = blockIdx.x * blockDim.x + threadIdx.x;
    if (i < n) {
        float As = sigma[i] * LOG2E;
        float w = W[i];
        out[i] = make_float4(-As * S15,
                             fmaf(As * mu[i], S15, B_CONST),
                             w, w * erev[i]);
    }
}

// Block: 1024 threads = (u: 0..255) x (h: j-quarter 0..3). RB=4 rows/block.
// Grid 512 blocks -> 2 blocks/CU x 16 waves = 32 waves/CU (100% occupancy).
__global__ __launch_bounds__(1024, 8) void ltc_kernel(
    const float4* __restrict__ rp,    // [UNITS][UNITS] recurrent params
    const float4* __restrict__ sp,    // [IN_DIM][UNITS] sensory params
    const float* __restrict__ inputs, // [BATCH][IN_DIM]
    const float* __restrict__ state,  // [BATCH][UNITS]
    const float* __restrict__ vleak,
    const float* __restrict__ gleak,
    const float* __restrict__ cm_t,
    float* __restrict__ out)          // [BATCH][UNITS]
{
    const int tid = threadIdx.x;
    const int u = tid & (UNITS - 1);
    const int h = tid >> 8;           // j-quarter 0..3
    const int b0 = blockIdx.x * RB;

    __shared__ __align__(16) float v_sh[RB][UNITS];
    __shared__ __align__(16) float in_sh[RB][IN_DIM];
    __shared__ float nb_sh[RB][UNITS];     // glvl + snum
    __shared__ float db_sh[RB][UNITS];     // cm + gl + sden + EPS
    __shared__ float cm_sh[UNITS];
    __shared__ float pred[NH][RB][UNITS];  // per-quarter partial w_red
    __shared__ float pnum[NH][RB][UNITS];  // per-quarter partial w_num

    // ---- stage rows (one element per thread) ----
    {
        int rb = tid >> 8, uu = tid & 255;   // 1024 slots = RB x UNITS
        float s = state[(b0 + rb) * UNITS + uu];
        v_sh[rb][uu] = fminf(fmaxf(s, -VCLAMP), VCLAMP);
        if (tid < RB * IN_DIM) {
            int rbi = tid >> 7, i = tid & (IN_DIM - 1);
            float x = inputs[(b0 + rbi) * IN_DIM + i];
            in_sh[rbi][i] = fminf(fmaxf(x, -VCLAMP), VCLAMP);
        }
        if (h == 0) cm_sh[u] = cm_t[u];
    }
    // exact f32 v for this thread's row (rb = h)
    float vfull = state[(b0 + h) * UNITS + u];
    __syncthreads();

    // ---- sensory path: quarter h sums i in [h*32, h*32+32) ----
    {
        float sden[RB] = {0.f, 0.f, 0.f, 0.f};
        float snum[RB] = {0.f, 0.f, 0.f, 0.f};
        const int ibase = h * (IN_DIM / NH);
        for (int ic = 0; ic < IN_DIM / NH; ic += 4) {
            const int i = ibase + ic;
            float4 q0 = sp[(i + 0) * UNITS + u];
            float4 q1 = sp[(i + 1) * UNITS + u];
            float4 q2 = sp[(i + 2) * UNITS + u];
            float4 q3 = sp[(i + 3) * UNITS + u];
            #pragma unroll
            for (int rb = 0; rb < RB; ++rb) {
                float4 x4 = *reinterpret_cast<const float4*>(&in_sh[rb][i]);
                syn1(q0, x4.x, sden[rb], snum[rb]);
                syn1(q1, x4.y, sden[rb], snum[rb]);
                syn1(q2, x4.z, sden[rb], snum[rb]);
                syn1(q3, x4.w, sden[rb], snum[rb]);
            }
        }
        #pragma unroll
        for (int rb = 0; rb < RB; ++rb) {
            pred[h][rb][u] = sden[rb];
            pnum[h][rb][u] = snum[rb];
        }
    }
    __syncthreads();

    // combine sensory partials: thread (u,h) owns row rb = h
    {
        float gl = gleak[u];
        float sd = pred[0][h][u] + pred[1][h][u] + pred[2][h][u] + pred[3][h][u];
        float sn = pnum[0][h][u] + pnum[1][h][u] + pnum[2][h][u] + pnum[3][h][u];
        db_sh[h][u] = cm_sh[u] + gl + sd + EPS;
        nb_sh[h][u] = fmaf(gl, vleak[u], sn);
    }
    __syncthreads();

    // ---- 12 folds: quarter h reduces j in [h*64, h*64+64) ----
    for (int f = 0; f < NFOLDS; ++f) {
        float wred[RB] = {0.f, 0.f, 0.f, 0.f};
        float wnum[RB] = {0.f, 0.f, 0.f, 0.f};
        const int jbase = h * (UNITS / NH);
        for (int jc = 0; jc < UNITS / NH; jc += 4) {
            const int j = jbase + jc;
            float4 q0 = rp[(j + 0) * UNITS + u];
            float4 q1 = rp[(j + 1) * UNITS + u];
            float4 q2 = rp[(j + 2) * UNITS + u];
            float4 q3 = rp[(j + 3) * UNITS + u];
            #pragma unroll
            for (int rb = 0; rb < RB; ++rb) {
                float4 v4 = *reinterpret_cast<const float4*>(&v_sh[rb][j]);
                syn1(q0, v4.x, wred[rb], wnum[rb]);
                syn1(q1, v4.y, wred[rb], wnum[rb]);
                syn1(q2, v4.z, wred[rb], wnum[rb]);
                syn1(q3, v4.w, wred[rb], wnum[rb]);
            }
        }
        #pragma unroll
        for (int rb = 0; rb < RB; ++rb) {
            pred[h][rb][u] = wred[rb];
            pnum[h][rb][u] = wnum[rb];
        }
        __syncthreads();

        // epilogue: thread (u,h) owns row rb = h
        {
            float wr = pred[0][h][u] + pred[1][h][u] + pred[2][h][u] + pred[3][h][u];
            float wn = pnum[0][h][u] + pnum[1][h][u] + pnum[2][h][u] + pnum[3][h][u];
            float num = fmaf(cm_sh[u], vfull, nb_sh[h][u]) + wn;
            float den = db_sh[h][u] + wr;
            float vn = num * RCPF(den);
            vfull = vn;                                   // exact v for cm*v
            v_sh[h][u] = fminf(fmaxf(vn, -VCLAMP), VCLAMP); // synapse input
            if (f == NFOLDS - 1)
                out[(b0 + h) * UNITS + u] = vn;
        }
        __syncthreads();
    }
}

extern "C" void kernel_launch(void* const* d_in, const int* in_sizes, int n_in,
                              void* d_out, int out_size, void* d_ws, size_t ws_size,
                              hipStream_t stream) {
    const float* inputs       = (const float*)d_in[0];
    const float* state        = (const float*)d_in[1];
    const float* sensory_mu   = (const float*)d_in[2];
    const float* sensory_sig  = (const float*)d_in[3];
    const float* sensory_W    = (const float*)d_in[4];
    const float* sensory_erev = (const float*)d_in[5];
    const float* mu           = (const float*)d_in[6];
    const float* sigma        = (const float*)d_in[7];
    const float* W            = (const float*)d_in[8];
    const float* erev         = (const float*)d_in[9];
    const float* vleak        = (const float*)d_in[10];
    const float* gleak        = (const float*)d_in[11];
    const float* cm_t         = (const float*)d_in[12];
    float* out = (float*)d_out;

    // workspace: rp (256x256 float4 = 1MB) | sp (128x256 float4 = 512KB)
    float4* rp = (float4*)d_ws;
    float4* sp = rp + UNITS * UNITS;

    int n_rec = UNITS * UNITS;   // 65536
    int n_sen = IN_DIM * UNITS;  // 32768
    prep_kernel<<<(n_rec + 255) / 256, 256, 0, stream>>>(mu, sigma, W, erev, rp, n_rec);
    prep_kernel<<<(n_sen + 255) / 256, 256, 0, stream>>>(
        sensory_mu, sensory_sig, sensory_W, sensory_erev, sp, n_sen);

    ltc_kernel<<<BATCH / RB, RB * UNITS, 0, stream>>>(rp, sp, inputs, state,
                                                      vleak, gleak, cm_t, out);
}